// Round 7
// baseline (4021.365 us; speedup 1.0000x reference)
//
#include <hip/hip_runtime.h>
#include <stdint.h>

// FPS (farthest point sampling), faithful to the reference:
//   dist = max(dist, ||p - last||)  (running MAX, per tf.maximum quirk)
//   idx  = argmax(dist)             (first-index tie-break)
// B=16, N=65536, npoint=1024 -> 1023 sequential rounds per batch.
//
// Round 7 change: pin px/py/pz/dist into VGPRs via empty asm. Round-6
// counters showed VGPR_Count=28 -> the compiler was NOT keeping the
// 32-float per-thread state in registers (remat/spill through L2),
// making the inner loop L2-bound. Pinning forces register residency.

#define B_      16
#define N_      65536
#define STEPS   1023       // npoint - 1
#define KBLK    16         // blocks per batch
#define THREADS 512
#define PPT     8          // points per thread = N_/KBLK/THREADS
#define PTS_PER_BLK (N_/KBLK)   // 4096

__global__ void zero_slots(unsigned long long* ws, int n) {
    int i = blockIdx.x * blockDim.x + threadIdx.x;
    if (i < n) ws[i] = 0ull;
}

__launch_bounds__(THREADS, 2)
__global__ void fps_kernel(const float* __restrict__ xyz,
                           float* __restrict__ out,
                           unsigned long long* __restrict__ slots) {
    #pragma clang fp contract(off)

    const int blk  = blockIdx.x;
    const int b    = blk >> 4;     // batch
    const int k    = blk & 15;     // sub-block within batch
    const int tid  = threadIdx.x;
    const int wid  = tid >> 6;
    const int lane = tid & 63;

    const float* bx = xyz + (size_t)b * (N_ * 3);
    const int pbase = k * PTS_PER_BLK + tid * PPT;

    // ---- one-time load of my 8 points (96B contiguous, 6x float4) ----
    float a[24];
    const float4* src = (const float4*)(bx + (size_t)pbase * 3);
    #pragma unroll
    for (int j = 0; j < 6; ++j) {
        float4 v = src[j];
        a[4*j+0] = v.x; a[4*j+1] = v.y; a[4*j+2] = v.z; a[4*j+3] = v.w;
    }
    float px[PPT], py[PPT], pz[PPT], dist[PPT];
    #pragma unroll
    for (int p = 0; p < PPT; ++p) {
        px[p] = a[3*p]; py[p] = a[3*p+1]; pz[p] = a[3*p+2];
        dist[p] = 0.0f;
    }
    // Pin per-thread state into VGPRs: asm results cannot be
    // rematerialized from global memory, so the 1023-step loop keeps
    // them register-resident (cost: 0 instructions).
    #pragma unroll
    for (int p = 0; p < PPT; ++p) {
        asm volatile("" : "+v"(px[p]), "+v"(py[p]), "+v"(pz[p]), "+v"(dist[p]));
    }

    // initial center = point 0 of this batch
    float cx = bx[0], cy = bx[1], cz = bx[2];

    float* bout = out + (size_t)b * (1024 * 3);
    if (k == 0 && tid == 0) { bout[0] = cx; bout[1] = cy; bout[2] = cz; }

    __shared__ float lval[THREADS / 64];
    __shared__ int   lidx[THREADS / 64];
    __shared__ int   winIdx;

    unsigned long long* batchSlots = slots + (size_t)b * KBLK;

    for (int s = 0; s < STEPS; ++s) {
        // ---- local update + local argmax (ascending index => first-max) ----
        float bv = -1.0f; int bp = 0;
        #pragma unroll
        for (int p = 0; p < PPT; ++p) {
            float dx = px[p] - cx, dy = py[p] - cy, dz = pz[p] - cz;
            float sq = dx*dx + dy*dy + dz*dz;   // no fma (contract off)
            float d  = sqrtf(sq);               // correctly-rounded
            float nd = fmaxf(dist[p], d);
            dist[p] = nd;
            if (nd > bv) { bv = nd; bp = p; }   // strict > keeps earliest idx
        }
        int gi = pbase + bp;

        // ---- wave reduce (val desc, idx asc on tie) ----
        #pragma unroll
        for (int m = 1; m < 64; m <<= 1) {
            float ov = __shfl_xor(bv, m);
            int   oi = __shfl_xor(gi, m);
            if (ov > bv || (ov == bv && oi < gi)) { bv = ov; gi = oi; }
        }
        if (lane == 0) { lval[wid] = bv; lidx[wid] = gi; }
        __syncthreads();   // B1

        if (wid == 0) {
            float v2 = (lane < THREADS/64) ? lval[lane] : -1.0f;
            int   i2 = (lane < THREADS/64) ? lidx[lane] : 0x7FFFFFFF;
            #pragma unroll
            for (int m = 1; m < THREADS/64; m <<= 1) {
                float ov = __shfl_xor(v2, m);
                int   oi = __shfl_xor(i2, m);
                if (ov > v2 || (ov == v2 && oi < i2)) { v2 = ov; i2 = oi; }
            }
            // lane 0 publishes this block's best as a step-tagged key:
            //   key = (s+1)<<48 | fp32bits(val)<<16 | (0xFFFF ^ idx)
            // u64 max = (max val, tie -> min idx); tag strictly increases
            // so stale keys never outrank fresh ones (no ABA, no zeroing).
            if (lane == 0) {
                unsigned long long key =
                    ((unsigned long long)(s + 1) << 48) |
                    ((unsigned long long)__float_as_uint(v2) << 16) |
                    (unsigned long long)(0xFFFFu ^ (unsigned)i2);
                __hip_atomic_store(&batchSlots[k], key,
                                   __ATOMIC_RELEASE, __HIP_MEMORY_SCOPE_AGENT);
            }
            // poll all 16 slots until every tag == s+1 (bounded guard)
            const unsigned long long want = (unsigned long long)(s + 1);
            unsigned long long myv = 0ull;
            const int slot = lane & 15;
            int guard = 0;
            for (;;) {
                myv = __hip_atomic_load(&batchSlots[slot],
                                        __ATOMIC_RELAXED, __HIP_MEMORY_SCOPE_AGENT);
                if (__all((myv >> 48) == want)) break;
                if (++guard > 100000) break;   // bounded: never hang
            }
            // max over 16 slots (lanes repeat with period 16)
            #pragma unroll
            for (int m = 1; m < 16; m <<= 1) {
                unsigned long long ov = __shfl_xor(myv, m);
                if (ov > myv) myv = ov;
            }
            if (lane == 0)
                winIdx = (int)(0xFFFFu ^ (unsigned)(myv & 0xFFFFull));
        }
        __syncthreads();   // B2

        const int wi = winIdx;
        const float* cp = bx + (size_t)wi * 3;  // read-only data: any cache ok
        cx = cp[0]; cy = cp[1]; cz = cp[2];

        if (k == 0 && tid == 0) {
            float* o = bout + (size_t)(s + 1) * 3;
            o[0] = cx; o[1] = cy; o[2] = cz;
        }
    }
}

extern "C" void kernel_launch(void* const* d_in, const int* in_sizes, int n_in,
                              void* d_out, int out_size, void* d_ws, size_t ws_size,
                              hipStream_t stream) {
    const float* xyz = (const float*)d_in[0];
    float* out = (float*)d_out;
    unsigned long long* slots = (unsigned long long*)d_ws;

    const int nslots = B_ * KBLK;   // 256 u64 = 2 KB
    zero_slots<<<1, 256, 0, stream>>>(slots, nslots);
    fps_kernel<<<B_ * KBLK, THREADS, 0, stream>>>(xyz, out, slots);
}

// Round 8
// 2949.832 us; speedup vs baseline: 1.3633x; 1.3633x over previous
//
#include <hip/hip_runtime.h>
#include <stdint.h>

// FPS (farthest point sampling), faithful to the reference:
//   dist = max(dist, ||p - last||)  (running MAX, per tf.maximum quirk)
//   idx  = argmax(dist)             (first-index tie-break)
// B=16, N=65536, npoint=1024 -> 1023 sequential rounds per batch.
//
// Round 8 changes (from counter evidence VGPR_Count=28, rounds 6-7):
//  1. Points live in LDS SoA (spx/spy/spz, 48 KB/block) — compiler refused
//     register residency (28 VGPRs < 32 state floats); LDS is explicit and
//     conflict-free (lane-stride-1 ds_read_b32). Only dist[8] in regs.
//  2. Winner COORDS are published through the combine slots (4 self-tagged
//     u64 words per block), so the winner's xyz arrives with the poll data
//     via shfl — no dependent global fetch on the serial chain.
//  3. Slot buffers double-buffered by step parity — removes the
//     fast-block-clobbers-slow-block race of the single-buffer scheme.

#define B_      16
#define N_      65536
#define STEPS   1023       // npoint - 1
#define KBLK    16         // blocks per batch
#define THREADS 512
#define PPT     8          // points per thread = N_/KBLK/THREADS
#define PTS     4096       // points per block
#define NW      (THREADS/64)   // 8 waves

__global__ void zero_slots(unsigned long long* ws, int n) {
    int i = blockIdx.x * blockDim.x + threadIdx.x;
    if (i < n) ws[i] = 0ull;
}

__launch_bounds__(THREADS)
__global__ void fps_kernel(const float* __restrict__ xyz,
                           float* __restrict__ out,
                           unsigned long long* __restrict__ slots) {
    #pragma clang fp contract(off)

    const int blk  = blockIdx.x;
    const int b    = blk >> 4;     // batch
    const int k    = blk & 15;     // sub-block within batch
    const int tid  = threadIdx.x;
    const int wid  = tid >> 6;
    const int lane = tid & 63;

    const float* bx = xyz + (size_t)b * (N_ * 3);

    __shared__ float spx[PTS], spy[PTS], spz[PTS];   // 48 KB
    __shared__ float lval[NW];
    __shared__ int   lidx[NW];
    __shared__ float wc[3];

    // ---- one-time: coalesced 96B/thread global read, scatter to LDS SoA ----
    {
        const float4* src = (const float4*)(bx + (size_t)(k * PTS + tid * PPT) * 3);
        float a[24];
        #pragma unroll
        for (int j = 0; j < 6; ++j) {
            float4 v = src[j];
            a[4*j+0] = v.x; a[4*j+1] = v.y; a[4*j+2] = v.z; a[4*j+3] = v.w;
        }
        #pragma unroll
        for (int p = 0; p < PPT; ++p) {
            int l = tid * PPT + p;
            spx[l] = a[3*p]; spy[l] = a[3*p+1]; spz[l] = a[3*p+2];
        }
    }
    float dist[PPT];
    #pragma unroll
    for (int p = 0; p < PPT; ++p) dist[p] = 0.0f;

    // initial center = point 0 of this batch
    float cx = bx[0], cy = bx[1], cz = bx[2];

    float* bout = out + (size_t)b * (1024 * 3);
    if (k == 0 && tid == 0) { bout[0] = cx; bout[1] = cy; bout[2] = cz; }
    __syncthreads();   // LDS points ready

    // slot layout: [parity][batch][word 0..3][block 0..15] u64
    unsigned long long* base = slots + (size_t)b * (4 * KBLK);
    const size_t parStride = (size_t)B_ * 4 * KBLK;   // u64s per parity buffer

    for (int s = 0; s < STEPS; ++s) {
        // ---- local update + local argmax (ascending l => first-max) ----
        float bv = -1.0f; int bl = 0;
        #pragma unroll
        for (int j = 0; j < PPT; ++j) {
            int l = tid + j * THREADS;            // stride-512: conflict-free
            float x = spx[l], y = spy[l], z = spz[l];
            float dx = x - cx, dy = y - cy, dz = z - cz;
            float sq = dx*dx + dy*dy + dz*dz;     // no fma (contract off)
            float d  = sqrtf(sq);                 // correctly-rounded
            float nd = fmaxf(dist[j], d);
            dist[j] = nd;
            if (nd > bv) { bv = nd; bl = l; }     // strict > keeps smallest l
        }
        int gi = k * PTS + bl;                    // within-batch global index

        // ---- wave reduce (val desc, idx asc on tie) ----
        #pragma unroll
        for (int m = 1; m < 64; m <<= 1) {
            float ov = __shfl_xor(bv, m);
            int   oi = __shfl_xor(gi, m);
            if (ov > bv || (ov == bv && oi < gi)) { bv = ov; gi = oi; }
        }
        if (lane == 0) { lval[wid] = bv; lidx[wid] = gi; }
        __syncthreads();   // B1

        if (wid == 0) {
            float v2 = (lane < NW) ? lval[lane] : -1.0f;
            int   i2 = (lane < NW) ? lidx[lane] : 0x7FFFFFFF;
            #pragma unroll
            for (int m = 1; m < NW; m <<= 1) {
                float ov = __shfl_xor(v2, m);
                int   oi = __shfl_xor(i2, m);
                if (ov > v2 || (ov == v2 && oi < i2)) { v2 = ov; i2 = oi; }
            }
            // all lanes of wave 0 now hold the block best (v2, i2).
            // Fetch its coords from our own LDS (uniform addr = broadcast).
            int li = i2 & (PTS - 1);
            float wx = spx[li], wy = spy[li], wz = spz[li];

            // publish 4 self-tagged words; u64-max on word A implements
            // (max val, tie -> min idx); tag == s+1 validates freshness.
            unsigned long long tag = (unsigned long long)(s + 1) << 48;
            unsigned long long A  = tag |
                ((unsigned long long)__float_as_uint(v2) << 16) |
                (unsigned long long)(0xFFFFu ^ (unsigned)i2);
            unsigned long long Bw = tag | (unsigned long long)__float_as_uint(wx);
            unsigned long long Cw = tag | (unsigned long long)__float_as_uint(wy);
            unsigned long long Dw = tag | (unsigned long long)__float_as_uint(wz);

            unsigned long long* cur = base + (size_t)(s & 1) * parStride;
            unsigned long long pub = (lane == 0) ? A :
                                     (lane == 1) ? Bw :
                                     (lane == 2) ? Cw : Dw;
            if (lane < 4)
                __hip_atomic_store(&cur[lane * KBLK + k], pub,
                                   __ATOMIC_RELAXED, __HIP_MEMORY_SCOPE_AGENT);

            // poll: lane i watches word (i>>4) of block (i&15) — coalesced.
            const unsigned long long want = (unsigned long long)(s + 1);
            unsigned long long pw = 0ull;
            int guard = 0;
            for (;;) {
                pw = __hip_atomic_load(&cur[lane],
                                       __ATOMIC_RELAXED, __HIP_MEMORY_SCOPE_AGENT);
                if (__all((pw >> 48) == want)) break;
                if (++guard > 200000) break;   // unreachable; bounds any stall
            }
            // A-word max within the 16-lane group (masks <=8 stay in-group)
            unsigned long long mm = pw;
            #pragma unroll
            for (int m = 1; m < 16; m <<= 1) {
                unsigned long long o = __shfl_xor(mm, m);
                if (o > mm) mm = o;
            }
            int gidx = 0xFFFF ^ (int)(mm & 0xFFFFull);  // valid in lanes 0-15
            gidx = __shfl(gidx, 0);
            int w = gidx >> 12;                         // winning block
            unsigned xlo = (unsigned)__shfl((int)(unsigned)pw, 16 + w);
            unsigned ylo = (unsigned)__shfl((int)(unsigned)pw, 32 + w);
            unsigned zlo = (unsigned)__shfl((int)(unsigned)pw, 48 + w);
            if (lane == 0) {
                wc[0] = __uint_as_float(xlo);
                wc[1] = __uint_as_float(ylo);
                wc[2] = __uint_as_float(zlo);
            }
        }
        __syncthreads();   // B2

        cx = wc[0]; cy = wc[1]; cz = wc[2];
        if (k == 0 && tid == 0) {
            float* o = bout + (size_t)(s + 1) * 3;
            o[0] = cx; o[1] = cy; o[2] = cz;
        }
    }
}

extern "C" void kernel_launch(void* const* d_in, const int* in_sizes, int n_in,
                              void* d_out, int out_size, void* d_ws, size_t ws_size,
                              hipStream_t stream) {
    const float* xyz = (const float*)d_in[0];
    float* out = (float*)d_out;
    unsigned long long* slots = (unsigned long long*)d_ws;

    const int nslots = 2 * B_ * 4 * KBLK;   // 2048 u64 = 16 KB
    zero_slots<<<(nslots + 255) / 256, 256, 0, stream>>>(slots, nslots);
    fps_kernel<<<B_ * KBLK, THREADS, 0, stream>>>(xyz, out, slots);
}